// Round 2
// baseline (4072.834 us; speedup 1.0000x reference)
//
#include <hip/hip_runtime.h>

typedef unsigned short u16;
typedef __bf16 bf16_t;
typedef bf16_t bf16x8 __attribute__((ext_vector_type(8)));
typedef u16 u16x8 __attribute__((ext_vector_type(8)));
typedef float f32x4 __attribute__((ext_vector_type(4)));

#define LL 256
#define DD 512
#define SS 512

__device__ __forceinline__ u16 f2bf(float f) {
  unsigned u = __float_as_uint(f);
  u += 0x7fffu + ((u >> 16) & 1u);
  return (u16)(u >> 16);
}

union FragU { u16x8 u; bf16x8 h; };

__device__ __forceinline__ bf16x8 cvt8(const float* __restrict__ p) {
  float4 a = *(const float4*)p;
  float4 b = *(const float4*)(p + 4);
  FragU r;
  r.u[0] = f2bf(a.x); r.u[1] = f2bf(a.y); r.u[2] = f2bf(a.z); r.u[3] = f2bf(a.w);
  r.u[4] = f2bf(b.x); r.u[5] = f2bf(b.y); r.u[6] = f2bf(b.z); r.u[7] = f2bf(b.w);
  return r.h;
}

__device__ __forceinline__ float sigmoidf_(float v) { return 1.f / (1.f + __expf(-v)); }

// x (B,L,D) fp32 -> xbf [t][b][d] bf16 (transposed for per-step contiguity)
__global__ void xconv_kernel(const float* __restrict__ x, u16* __restrict__ xbf) {
  const size_t n8 = 16777216 / 8;
  for (size_t i = (size_t)blockIdx.x * blockDim.x + threadIdx.x; i < n8;
       i += (size_t)gridDim.x * blockDim.x) {
    size_t di = i * 8;
    int t = (int)(di >> 16);
    int rem = (int)(di & 65535);
    int b = rem >> 9, d = rem & 511;
    FragU f;
    f.h = cvt8(x + (size_t)b * 131072 + (size_t)t * 512 + d);
    *(u16x8*)(xbf + di) = f.u;
  }
}

#define MFMA(a, b, c) __builtin_amdgcn_mfma_f32_16x16x32_bf16(a, b, c, 0, 0, 0)

// Persistent scan kernel. 256 WGs = 4 batch-blocks x 64 column-groups; 4 waves split K.
// Weights live in VGPRs for all 256 steps; state lives in registers; h broadcast via
// double-buffered global + device-scope spin barrier once per step.
__global__ __launch_bounds__(256, 1) void persist_kernel(
    const float* __restrict__ x, const u16* __restrict__ xbf,
    const float* __restrict__ td,
    const float* __restrict__ w, const float* __restrict__ bias,
    const float* __restrict__ dw, const float* __restrict__ dbias,
    const float* __restrict__ dbeta,
    u16* __restrict__ hb, int* __restrict__ cnt,
    float* __restrict__ out) {
  __shared__ float P[4][64][36];
  const int wg = blockIdx.x, bb = wg >> 6, cg = wg & 63;
  const int tid = threadIdx.x, kq = tid >> 6, l = tid & 63;
  const int l15 = l & 15, lk = l >> 4;

  // ---- load this wave's B fragments into registers (held across all steps) ----
  bf16x8 wreg[8][4];
  const int kA = kq * 256 + lk * 8;  // this lane's K offset
  {
#pragma unroll
    for (int n = 0; n < 3; ++n) {
      int nl = n * 16 + l15;
      int grow = (nl >> 3) * SS + cg * 8 + (nl & 7);
      const float* wp = w + (size_t)grow * 1024 + kA;
#pragma unroll
      for (int ks = 0; ks < 8; ++ks) wreg[ks][n] = cvt8(wp + ks * 32);
    }
    if (l15 == 0) {
      const float* wp = dw + kA;
#pragma unroll
      for (int ks = 0; ks < 8; ++ks) wreg[ks][3] = cvt8(wp + ks * 32);
    } else {
#pragma unroll
      for (int ks = 0; ks < 8; ++ks) {
        FragU zf; zf.u = (u16x8){0, 0, 0, 0, 0, 0, 0, 0};
        wreg[ks][3] = zf.h;
      }
    }
  }

  // ---- per-thread state: thread owns (row r in block, state col j in group) ----
  const int r = tid >> 3, j = tid & 7;
  const int b = bb * 32 + r, s = cg * 8 + j;
  float bia[6];
#pragma unroll
  for (int g = 0; g < 6; ++g) bia[g] = bias[g * SS + s];
  const float dbia = dbias[0], beta = dbeta[0];
  float cs = 0.f, ce = 0.f, o = 0.f, dreg = 0.f;

  const int rA0 = bb * 32 + l15, rA1 = rA0 + 16;

  for (int t = 0; t < LL; ++t) {
    // [1] h_t from incoming carry; write to broadcast buffer + outputs
    float dt_t = td[(size_t)b * LL + t];
    float c_t = cs + (ce - cs) * __expf(-dreg * dt_t);
    float h_t = o * tanhf(c_t);
    u16* hcur = hb + (size_t)(t & 1) * 65536;
    hcur[(size_t)b * SS + s] = f2bf(h_t);
    out[((size_t)b * LL + t) * SS + s] = h_t;

    // [2] grid-wide barrier (device-scope release/acquire)
    __syncthreads();
    if (tid == 0) {
      __hip_atomic_fetch_add(cnt, 1, __ATOMIC_RELEASE, __HIP_MEMORY_SCOPE_AGENT);
      const int target = 256 * (t + 1);
      while (__hip_atomic_load(cnt, __ATOMIC_RELAXED, __HIP_MEMORY_SCOPE_AGENT) < target)
        __builtin_amdgcn_s_sleep(2);
      __builtin_amdgcn_fence(__ATOMIC_ACQUIRE, "agent");
    }
    __syncthreads();

    // [3] GEMM: waves 0,1 consume x_t; waves 2,3 consume h_t
    f32x4 acc[2][4] = {};
    if (kq < 2) {
      if (xbf) {
        const u16* xp = xbf + (size_t)t * 65536 + kA;
#pragma unroll
        for (int ks = 0; ks < 8; ++ks) {
          bf16x8 a0 = *(const bf16x8*)(xp + (size_t)rA0 * 512 + ks * 32);
          bf16x8 a1 = *(const bf16x8*)(xp + (size_t)rA1 * 512 + ks * 32);
#pragma unroll
          for (int n = 0; n < 4; ++n) {
            acc[0][n] = MFMA(a0, wreg[ks][n], acc[0][n]);
            acc[1][n] = MFMA(a1, wreg[ks][n], acc[1][n]);
          }
        }
      } else {
        const float* xp = x + (size_t)t * 512 + kA;
#pragma unroll
        for (int ks = 0; ks < 8; ++ks) {
          bf16x8 a0 = cvt8(xp + (size_t)rA0 * 131072 + ks * 32);
          bf16x8 a1 = cvt8(xp + (size_t)rA1 * 131072 + ks * 32);
#pragma unroll
          for (int n = 0; n < 4; ++n) {
            acc[0][n] = MFMA(a0, wreg[ks][n], acc[0][n]);
            acc[1][n] = MFMA(a1, wreg[ks][n], acc[1][n]);
          }
        }
      }
    } else {
      const u16* hp = hcur + (kA - 512);
#pragma unroll
      for (int ks = 0; ks < 8; ++ks) {
        bf16x8 a0 = *(const bf16x8*)(hp + (size_t)rA0 * 512 + ks * 32);
        bf16x8 a1 = *(const bf16x8*)(hp + (size_t)rA1 * 512 + ks * 32);
#pragma unroll
        for (int n = 0; n < 4; ++n) {
          acc[0][n] = MFMA(a0, wreg[ks][n], acc[0][n]);
          acc[1][n] = MFMA(a1, wreg[ks][n], acc[1][n]);
        }
      }
    }

    // spill partial sums for cross-wave K reduction
#pragma unroll
    for (int m = 0; m < 2; ++m)
#pragma unroll
      for (int n = 0; n < 4; ++n)
        *(f32x4*)&P[kq][n * 16 + l15][m * 16 + lk * 4] = acc[m][n];
    __syncthreads();

    // [4] gates + state update (registers)
    float pre[6];
#pragma unroll
    for (int g = 0; g < 6; ++g) {
      int col = g * 8 + j;
      pre[g] = P[0][col][r] + P[1][col][r] + P[2][col][r] + P[3][col][r] + bia[g];
    }
    float dpre = P[0][48][r] + P[1][48][r] + P[2][48][r] + P[3][48][r] + dbia;

    float ig  = sigmoidf_(pre[0]);
    float fg  = sigmoidf_(pre[1]);
    float ieg = sigmoidf_(pre[2]);
    float feg = sigmoidf_(pre[3]);
    float z   = 2.f * sigmoidf_(pre[4]) - 1.f;
    float og  = sigmoidf_(pre[5]);

    cs = fg * c_t + ig * z;
    ce = feg * ce + ieg * z;
    o = og;
    float v = beta * dpre;
    float sp = (v > 15.f) ? v : log1pf(__expf(v));
    dreg = sp / beta;
    // P is re-read only until here; next overwrite is after the [2] barrier of t+1.
  }

  // final_state = concat([o, cs, ce, d], axis=1), shape (1, 128, 1537)
  size_t fb = (size_t)16777216 + (size_t)b * 1537;
  out[fb + s] = o;
  out[fb + 512 + s] = cs;
  out[fb + 1024 + s] = ce;
  if (s == 0) out[fb + 1536] = dreg;
}

extern "C" void kernel_launch(void* const* d_in, const int* in_sizes, int n_in,
                              void* d_out, int out_size, void* d_ws, size_t ws_size,
                              hipStream_t stream) {
  const float* x     = (const float*)d_in[0];
  const float* td    = (const float*)d_in[1];
  const float* w     = (const float*)d_in[2];
  const float* bias  = (const float*)d_in[3];
  const float* dw    = (const float*)d_in[4];
  const float* dbias = (const float*)d_in[5];
  const float* dbeta = (const float*)d_in[6];
  float* out = (float*)d_out;

  char* ws = (char*)d_ws;
  u16* hb  = (u16*)ws;                    // [2][128][512] bf16 = 262,144 B
  int* cnt = (int*)(ws + 262144);         // barrier counter
  const size_t XBF_OFF = 262400;
  const size_t NEED = XBF_OFF + 33554432; // + xbf [256][128][512] bf16
  u16* xbf = (ws_size >= NEED) ? (u16*)(ws + XBF_OFF) : nullptr;

  hipMemsetAsync(cnt, 0, 4, stream);
  if (xbf) hipLaunchKernelGGL(xconv_kernel, dim3(2048), dim3(256), 0, stream, x, xbf);
  hipLaunchKernelGGL(persist_kernel, dim3(256), dim3(256), 0, stream,
                     x, xbf, td, w, bias, dw, dbias, dbeta, hb, cnt, out);
}

// Round 3
// 3590.027 us; speedup vs baseline: 1.1345x; 1.1345x over previous
//
#include <hip/hip_runtime.h>

typedef unsigned short u16;
typedef unsigned long long u64;
typedef __bf16 bf16_t;
typedef bf16_t bf16x8 __attribute__((ext_vector_type(8)));
typedef u16 u16x8 __attribute__((ext_vector_type(8)));
typedef float f32x4 __attribute__((ext_vector_type(4)));

#define LL 256
#define DD 512
#define SS 512

__device__ __forceinline__ u16 f2bf(float f) {
  unsigned u = __float_as_uint(f);
  u += 0x7fffu + ((u >> 16) & 1u);
  return (u16)(u >> 16);
}

union FragU { u16x8 u; bf16x8 h; u64 q[2]; };

__device__ __forceinline__ bf16x8 cvt8(const float* __restrict__ p) {
  float4 a = *(const float4*)p;
  float4 b = *(const float4*)(p + 4);
  FragU r;
  r.u[0] = f2bf(a.x); r.u[1] = f2bf(a.y); r.u[2] = f2bf(a.z); r.u[3] = f2bf(a.w);
  r.u[4] = f2bf(b.x); r.u[5] = f2bf(b.y); r.u[6] = f2bf(b.z); r.u[7] = f2bf(b.w);
  return r.h;
}

__device__ __forceinline__ float sigmoidf_(float v) { return 1.f / (1.f + __expf(-v)); }

// x (B,L,D) fp32 -> xbf [t][b][d] bf16
__global__ void xconv_kernel(const float* __restrict__ x, u16* __restrict__ xbf) {
  const size_t n8 = 16777216 / 8;
  for (size_t i = (size_t)blockIdx.x * blockDim.x + threadIdx.x; i < n8;
       i += (size_t)gridDim.x * blockDim.x) {
    size_t di = i * 8;
    int t = (int)(di >> 16);
    int rem = (int)(di & 65535);
    int b = rem >> 9, d = rem & 511;
    FragU f;
    f.h = cvt8(x + (size_t)b * 131072 + (size_t)t * 512 + d);
    *(u16x8*)(xbf + di) = f.u;
  }
}

#define MFMA(a, b, c) __builtin_amdgcn_mfma_f32_16x16x32_bf16(a, b, c, 0, 0, 0)

// Persistent scan. 256 WGs = 4 batch-blocks x 64 col-groups; 4 waves split K=1024.
// Weights in VGPRs; state in registers. Cross-WG h exchange via fine-grained
// LLC-coherent (sc0 sc1) relaxed agent atomics -- NO agent fences, no L2 wb/inv.
__global__ __launch_bounds__(256, 1) void persist_kernel(
    const float* __restrict__ x, const u16* __restrict__ xbf,
    const float* __restrict__ td,
    const float* __restrict__ w, const float* __restrict__ bias,
    const float* __restrict__ dw, const float* __restrict__ dbias,
    const float* __restrict__ dbeta,
    u16* __restrict__ hb, int* __restrict__ cnt,
    float* __restrict__ out) {
  __shared__ float P[4][64][36];
  const int wg = blockIdx.x, bb = wg >> 6, cg = wg & 63;
  const int tid = threadIdx.x, kq = tid >> 6, l = tid & 63;
  const int l15 = l & 15, lk = l >> 4;

  // ---- B fragments into registers (held for all 256 steps) ----
  bf16x8 wreg[8][4];
  const int kA = kq * 256 + lk * 8;
  {
#pragma unroll
    for (int n = 0; n < 3; ++n) {
      int nl = n * 16 + l15;
      int grow = (nl >> 3) * SS + cg * 8 + (nl & 7);
      const float* wp = w + (size_t)grow * 1024 + kA;
#pragma unroll
      for (int ks = 0; ks < 8; ++ks) wreg[ks][n] = cvt8(wp + ks * 32);
    }
    if (l15 == 0) {
      const float* wp = dw + kA;
#pragma unroll
      for (int ks = 0; ks < 8; ++ks) wreg[ks][3] = cvt8(wp + ks * 32);
    } else {
#pragma unroll
      for (int ks = 0; ks < 8; ++ks) {
        FragU zf; zf.u = (u16x8){0, 0, 0, 0, 0, 0, 0, 0};
        wreg[ks][3] = zf.h;
      }
    }
  }

  // ---- per-thread state ----
  const int r = tid >> 3, j = tid & 7;
  const int b = bb * 32 + r, s = cg * 8 + j;
  float bia[6];
#pragma unroll
  for (int g = 0; g < 6; ++g) bia[g] = bias[g * SS + s];
  const float dbia = dbias[0], beta = dbeta[0];
  float cs = 0.f, ce = 0.f, o = 0.f, dreg = 0.f;

  const int rA0 = bb * 32 + l15, rA1 = rA0 + 16;
  int* mycnt = cnt + bb * 64;  // per-batch-block counter, own cacheline

  for (int t = 0; t < LL; ++t) {
    // [1] h_t from carry; coherent store to broadcast buffer; plain store to out
    float dt_t = td[(size_t)b * LL + t];
    float c_t = cs + (ce - cs) * __expf(-dreg * dt_t);
    float h_t = o * tanhf(c_t);
    u16* hcur = hb + (size_t)(t & 1) * 65536;
    {
      unsigned hv = f2bf(h_t);
      unsigned nb = (unsigned)__shfl_down((int)hv, 1, 64);
      if ((tid & 1) == 0) {
        unsigned packed = hv | (nb << 16);
        __hip_atomic_store((unsigned*)(hcur + (size_t)b * SS + s), packed,
                           __ATOMIC_RELAXED, __HIP_MEMORY_SCOPE_AGENT);
      }
    }
    out[((size_t)b * LL + t) * SS + s] = h_t;

    // [2] per-wave: drain stores, then signal arrival (relaxed -> no L2 wb)
    asm volatile("s_waitcnt vmcnt(0)" ::: "memory");
    if (l == 0)
      __hip_atomic_fetch_add(mycnt, 1, __ATOMIC_RELAXED, __HIP_MEMORY_SCOPE_AGENT);

    f32x4 acc[2][4] = {};
    const int target = 256 * (t + 1);

    if (kq < 2) {
      // [3a] x-waves: GEMM immediately (no h dependency) -- overlaps others' spin
      if (xbf) {
        const u16* xp = xbf + (size_t)t * 65536 + kA;
#pragma unroll
        for (int ks = 0; ks < 8; ++ks) {
          bf16x8 a0 = *(const bf16x8*)(xp + (size_t)rA0 * 512 + ks * 32);
          bf16x8 a1 = *(const bf16x8*)(xp + (size_t)rA1 * 512 + ks * 32);
#pragma unroll
          for (int n = 0; n < 4; ++n) {
            acc[0][n] = MFMA(a0, wreg[ks][n], acc[0][n]);
            acc[1][n] = MFMA(a1, wreg[ks][n], acc[1][n]);
          }
        }
      } else {
        const float* xp = x + (size_t)t * 512 + kA;
#pragma unroll
        for (int ks = 0; ks < 8; ++ks) {
          bf16x8 a0 = cvt8(xp + (size_t)rA0 * 131072 + ks * 32);
          bf16x8 a1 = cvt8(xp + (size_t)rA1 * 131072 + ks * 32);
#pragma unroll
          for (int n = 0; n < 4; ++n) {
            acc[0][n] = MFMA(a0, wreg[ks][n], acc[0][n]);
            acc[1][n] = MFMA(a1, wreg[ks][n], acc[1][n]);
          }
        }
      }
    } else {
      // [3b] h-waves: spin until all 256 producer-waves of this batch-block arrived
      while (__hip_atomic_load(mycnt, __ATOMIC_RELAXED, __HIP_MEMORY_SCOPE_AGENT) < target)
        __builtin_amdgcn_s_sleep(1);
      __builtin_amdgcn_fence(__ATOMIC_ACQUIRE, "workgroup");  // compiler ordering; no cache ops

      const u16* hp = hcur + (kA - 512);
#pragma unroll
      for (int ks = 0; ks < 8; ++ks) {
        FragU fa0, fa1;
        const u64* p0 = (const u64*)(hp + (size_t)rA0 * 512 + ks * 32);
        const u64* p1 = (const u64*)(hp + (size_t)rA1 * 512 + ks * 32);
        fa0.q[0] = __hip_atomic_load(p0, __ATOMIC_RELAXED, __HIP_MEMORY_SCOPE_AGENT);
        fa0.q[1] = __hip_atomic_load(p0 + 1, __ATOMIC_RELAXED, __HIP_MEMORY_SCOPE_AGENT);
        fa1.q[0] = __hip_atomic_load(p1, __ATOMIC_RELAXED, __HIP_MEMORY_SCOPE_AGENT);
        fa1.q[1] = __hip_atomic_load(p1 + 1, __ATOMIC_RELAXED, __HIP_MEMORY_SCOPE_AGENT);
#pragma unroll
        for (int n = 0; n < 4; ++n) {
          acc[0][n] = MFMA(fa0.h, wreg[ks][n], acc[0][n]);
          acc[1][n] = MFMA(fa1.h, wreg[ks][n], acc[1][n]);
        }
      }
    }

    // [4] spill partials, reduce, gates, state update
#pragma unroll
    for (int m = 0; m < 2; ++m)
#pragma unroll
      for (int n = 0; n < 4; ++n)
        *(f32x4*)&P[kq][n * 16 + l15][m * 16 + lk * 4] = acc[m][n];
    __syncthreads();

    float pre[6];
#pragma unroll
    for (int g = 0; g < 6; ++g) {
      int col = g * 8 + j;
      pre[g] = P[0][col][r] + P[1][col][r] + P[2][col][r] + P[3][col][r] + bia[g];
    }
    float dpre = P[0][48][r] + P[1][48][r] + P[2][48][r] + P[3][48][r] + dbia;

    float ig  = sigmoidf_(pre[0]);
    float fg  = sigmoidf_(pre[1]);
    float ieg = sigmoidf_(pre[2]);
    float feg = sigmoidf_(pre[3]);
    float z   = 2.f * sigmoidf_(pre[4]) - 1.f;
    float og  = sigmoidf_(pre[5]);

    cs = fg * c_t + ig * z;
    ce = feg * ce + ieg * z;
    o = og;
    float v = beta * dpre;
    float sp = (v > 15.f) ? v : log1pf(__expf(v));
    dreg = sp / beta;

    __syncthreads();  // gates of t done before anyone spills t+1 into P
  }

  size_t fb = (size_t)16777216 + (size_t)b * 1537;
  out[fb + s] = o;
  out[fb + 512 + s] = cs;
  out[fb + 1024 + s] = ce;
  if (s == 0) out[fb + 1536] = dreg;
}

extern "C" void kernel_launch(void* const* d_in, const int* in_sizes, int n_in,
                              void* d_out, int out_size, void* d_ws, size_t ws_size,
                              hipStream_t stream) {
  const float* x     = (const float*)d_in[0];
  const float* td    = (const float*)d_in[1];
  const float* w     = (const float*)d_in[2];
  const float* bias  = (const float*)d_in[3];
  const float* dw    = (const float*)d_in[4];
  const float* dbias = (const float*)d_in[5];
  const float* dbeta = (const float*)d_in[6];
  float* out = (float*)d_out;

  char* ws = (char*)d_ws;
  u16* hb  = (u16*)ws;                    // [2][128][512] bf16 = 262,144 B
  int* cnt = (int*)(ws + 262144);         // 4 counters, 256B apart (1 KB)
  const size_t XBF_OFF = 263168;
  const size_t NEED = XBF_OFF + 33554432;
  u16* xbf = (ws_size >= NEED) ? (u16*)(ws + XBF_OFF) : nullptr;

  hipMemsetAsync(cnt, 0, 1024, stream);
  if (xbf) hipLaunchKernelGGL(xconv_kernel, dim3(2048), dim3(256), 0, stream, x, xbf);
  hipLaunchKernelGGL(persist_kernel, dim3(256), dim3(256), 0, stream,
                     x, xbf, td, w, bias, dw, dbias, dbeta, hb, cnt, out);
}

// Round 4
// 2850.536 us; speedup vs baseline: 1.4288x; 1.2594x over previous
//
#include <hip/hip_runtime.h>

typedef unsigned short u16;
typedef unsigned long long u64;
typedef __bf16 bf16_t;
typedef bf16_t bf16x8 __attribute__((ext_vector_type(8)));
typedef u16 u16x8 __attribute__((ext_vector_type(8)));
typedef float f32x4 __attribute__((ext_vector_type(4)));

#define LL 256
#define DD 512
#define SS 512

__device__ __forceinline__ u16 f2bf(float f) {
  unsigned u = __float_as_uint(f);
  u += 0x7fffu + ((u >> 16) & 1u);
  return (u16)(u >> 16);
}

union FragU { u16x8 u; bf16x8 h; u64 q[2]; };

__device__ __forceinline__ bf16x8 cvt8(const float* __restrict__ p) {
  float4 a = *(const float4*)p;
  float4 b = *(const float4*)(p + 4);
  FragU r;
  r.u[0] = f2bf(a.x); r.u[1] = f2bf(a.y); r.u[2] = f2bf(a.z); r.u[3] = f2bf(a.w);
  r.u[4] = f2bf(b.x); r.u[5] = f2bf(b.y); r.u[6] = f2bf(b.z); r.u[7] = f2bf(b.w);
  return r.h;
}

__device__ __forceinline__ float sigmoidf_(float v) { return 1.f / (1.f + __expf(-v)); }

// x (B,L,D) fp32 -> xbf [t][b][d] bf16
__global__ void xconv_kernel(const float* __restrict__ x, u16* __restrict__ xbf) {
  const size_t n8 = 16777216 / 8;
  for (size_t i = (size_t)blockIdx.x * blockDim.x + threadIdx.x; i < n8;
       i += (size_t)gridDim.x * blockDim.x) {
    size_t di = i * 8;
    int t = (int)(di >> 16);
    int rem = (int)(di & 65535);
    int b = rem >> 9, d = rem & 511;
    FragU f;
    f.h = cvt8(x + (size_t)b * 131072 + (size_t)t * 512 + d);
    *(u16x8*)(xbf + di) = f.u;
  }
}

#define MFMA(a, b, c) __builtin_amdgcn_mfma_f32_16x16x32_bf16(a, b, c, 0, 0, 0)
#define ALOAD(p) __hip_atomic_load((p), __ATOMIC_RELAXED, __HIP_MEMORY_SCOPE_AGENT)
#define ASTORE(p, v) __hip_atomic_store((p), (v), __ATOMIC_RELAXED, __HIP_MEMORY_SCOPE_AGENT)

// Persistent scan. 256 WGs = 4 batch-blocks x 64 col-groups; 4 waves split K=1024.
// Weights in VGPRs; state in registers. Cross-WG sync: per-wave flag stores
// (zero same-address RMW contention) + coalesced vector polling. h exchanged via
// LLC-coherent relaxed agent atomics. No agent fences, no atomic RMWs anywhere.
__global__ __launch_bounds__(256, 1) void persist_kernel(
    const float* __restrict__ x, const u16* __restrict__ xbf,
    const float* __restrict__ td,
    const float* __restrict__ w, const float* __restrict__ bias,
    const float* __restrict__ dw, const float* __restrict__ dbias,
    const float* __restrict__ dbeta,
    u16* __restrict__ hb, int* __restrict__ flags,
    float* __restrict__ out) {
  __shared__ float P[2][4][64][36];  // double-buffered -> one barrier per step
  const int wg = blockIdx.x, bb = wg >> 6, cg = wg & 63;
  const int tid = threadIdx.x, kq = tid >> 6, l = tid & 63;
  const int l15 = l & 15, lk = l >> 4;

  // ---- B fragments into registers (held for all 256 steps) ----
  bf16x8 wreg[8][4];
  const int kA = kq * 256 + lk * 8;
  {
#pragma unroll
    for (int n = 0; n < 3; ++n) {
      int nl = n * 16 + l15;
      int grow = (nl >> 3) * SS + cg * 8 + (nl & 7);
      const float* wp = w + (size_t)grow * 1024 + kA;
#pragma unroll
      for (int ks = 0; ks < 8; ++ks) wreg[ks][n] = cvt8(wp + ks * 32);
    }
    if (l15 == 0) {
      const float* wp = dw + kA;
#pragma unroll
      for (int ks = 0; ks < 8; ++ks) wreg[ks][3] = cvt8(wp + ks * 32);
    } else {
#pragma unroll
      for (int ks = 0; ks < 8; ++ks) {
        FragU zf; zf.u = (u16x8){0, 0, 0, 0, 0, 0, 0, 0};
        wreg[ks][3] = zf.h;
      }
    }
  }

  // ---- per-thread state ----
  const int r = tid >> 3, j = tid & 7;
  const int b = bb * 32 + r, s = cg * 8 + j;
  float bia[6];
#pragma unroll
  for (int g = 0; g < 6; ++g) bia[g] = bias[g * SS + s];
  const float dbia = dbias[0], beta = dbeta[0];
  float cs = 0.f, ce = 0.f, o = 0.f, dreg = 0.f;

  const int rA0 = bb * 32 + l15, rA1 = rA0 + 16;
  int* myflag = flags + bb * 256 + cg * 4 + kq;      // this wave's private flag
  const int* pollp = flags + bb * 256 + l * 4;       // 4 flags per lane, 256 per bb
  float dtn = td[(size_t)b * LL];                    // prefetched dt for t=0

  for (int t = 0; t < LL; ++t) {
    // [1] h_t from carry; coherent packed store to broadcast buffer
    float dt_t = dtn;
    float c_t = cs + (ce - cs) * __expf(-dreg * dt_t);
    float h_t = o * (2.f * sigmoidf_(2.f * c_t) - 1.f);
    u16* hcur = hb + (size_t)(t & 1) * 65536;
    {
      unsigned hv = f2bf(h_t);
      unsigned nb = (unsigned)__shfl_down((int)hv, 1, 64);
      if ((tid & 1) == 0)
        ASTORE((unsigned*)(hcur + (size_t)b * SS + s), hv | (nb << 16));
    }

    // [2] drain h stores, then per-wave flag store (no RMW, no contention)
    asm volatile("s_waitcnt vmcnt(0)" ::: "memory");
    if (l == 0) ASTORE(myflag, t + 1);

    // deferred/overlapped work: output write + next dt prefetch
    out[((size_t)b * LL + t) * SS + s] = h_t;
    if (t + 1 < LL) dtn = td[(size_t)b * LL + (t + 1)];

    f32x4 acc[2][4] = {};
    if (kq < 2) {
      // [3a] x-waves: GEMM immediately (no h dependency)
      if (xbf) {
        const u16* xp = xbf + (size_t)t * 65536 + kA;
#pragma unroll
        for (int ks = 0; ks < 8; ++ks) {
          bf16x8 a0 = *(const bf16x8*)(xp + (size_t)rA0 * 512 + ks * 32);
          bf16x8 a1 = *(const bf16x8*)(xp + (size_t)rA1 * 512 + ks * 32);
#pragma unroll
          for (int n = 0; n < 4; ++n) {
            acc[0][n] = MFMA(a0, wreg[ks][n], acc[0][n]);
            acc[1][n] = MFMA(a1, wreg[ks][n], acc[1][n]);
          }
        }
      } else {
        const float* xp = x + (size_t)t * 512 + kA;
#pragma unroll
        for (int ks = 0; ks < 8; ++ks) {
          bf16x8 a0 = cvt8(xp + (size_t)rA0 * 131072 + ks * 32);
          bf16x8 a1 = cvt8(xp + (size_t)rA1 * 131072 + ks * 32);
#pragma unroll
          for (int n = 0; n < 4; ++n) {
            acc[0][n] = MFMA(a0, wreg[ks][n], acc[0][n]);
            acc[1][n] = MFMA(a1, wreg[ks][n], acc[1][n]);
          }
        }
      }
    } else {
      // [3b] h-waves: poll 256 flags of this batch-block (coalesced, read-only)
      const int tgt = t + 1;
      while (true) {
        int f0 = ALOAD(pollp + 0);
        int f1 = ALOAD(pollp + 1);
        int f2 = ALOAD(pollp + 2);
        int f3 = ALOAD(pollp + 3);
        int m = min(min(f0, f1), min(f2, f3));
        if (__all(m >= tgt)) break;
      }
      __builtin_amdgcn_fence(__ATOMIC_ACQUIRE, "workgroup");  // ordering only

      const u16* hp = hcur + (kA - 512);
#pragma unroll
      for (int ks = 0; ks < 8; ++ks) {
        FragU fa0, fa1;
        const u64* p0 = (const u64*)(hp + (size_t)rA0 * 512 + ks * 32);
        const u64* p1 = (const u64*)(hp + (size_t)rA1 * 512 + ks * 32);
        fa0.q[0] = ALOAD(p0);
        fa0.q[1] = ALOAD(p0 + 1);
        fa1.q[0] = ALOAD(p1);
        fa1.q[1] = ALOAD(p1 + 1);
#pragma unroll
        for (int n = 0; n < 4; ++n) {
          acc[0][n] = MFMA(fa0.h, wreg[ks][n], acc[0][n]);
          acc[1][n] = MFMA(fa1.h, wreg[ks][n], acc[1][n]);
        }
      }
    }

    // [4] spill partials (double-buffered), one barrier, reduce + gates
    const int pb = t & 1;
#pragma unroll
    for (int m = 0; m < 2; ++m)
#pragma unroll
      for (int n = 0; n < 4; ++n)
        *(f32x4*)&P[pb][kq][n * 16 + l15][m * 16 + lk * 4] = acc[m][n];
    __syncthreads();

    float pre[6];
#pragma unroll
    for (int g = 0; g < 6; ++g) {
      int col = g * 8 + j;
      pre[g] = P[pb][0][col][r] + P[pb][1][col][r] + P[pb][2][col][r] + P[pb][3][col][r] + bia[g];
    }
    float dpre = P[pb][0][48][r] + P[pb][1][48][r] + P[pb][2][48][r] + P[pb][3][48][r] + dbia;

    float ig  = sigmoidf_(pre[0]);
    float fg  = sigmoidf_(pre[1]);
    float ieg = sigmoidf_(pre[2]);
    float feg = sigmoidf_(pre[3]);
    float z   = 2.f * sigmoidf_(pre[4]) - 1.f;
    float og  = sigmoidf_(pre[5]);

    cs = fg * c_t + ig * z;
    ce = feg * ce + ieg * z;
    o = og;
    float v = beta * dpre;
    float sp = (v > 15.f) ? v : log1pf(__expf(v));
    dreg = sp / beta;
  }

  size_t fb = (size_t)16777216 + (size_t)b * 1537;
  out[fb + s] = o;
  out[fb + 512 + s] = cs;
  out[fb + 1024 + s] = ce;
  if (s == 0) out[fb + 1536] = dreg;
}

extern "C" void kernel_launch(void* const* d_in, const int* in_sizes, int n_in,
                              void* d_out, int out_size, void* d_ws, size_t ws_size,
                              hipStream_t stream) {
  const float* x     = (const float*)d_in[0];
  const float* td    = (const float*)d_in[1];
  const float* w     = (const float*)d_in[2];
  const float* bias  = (const float*)d_in[3];
  const float* dw    = (const float*)d_in[4];
  const float* dbias = (const float*)d_in[5];
  const float* dbeta = (const float*)d_in[6];
  float* out = (float*)d_out;

  char* ws = (char*)d_ws;
  u16* hb    = (u16*)ws;                  // [2][128][512] bf16 = 262,144 B
  int* flags = (int*)(ws + 262144);       // [4][64][4] ints = 4 KB
  const size_t XBF_OFF = 266240;
  const size_t NEED = XBF_OFF + 33554432;
  u16* xbf = (ws_size >= NEED) ? (u16*)(ws + XBF_OFF) : nullptr;

  hipMemsetAsync(flags, 0, 4096, stream);
  if (xbf) hipLaunchKernelGGL(xconv_kernel, dim3(2048), dim3(256), 0, stream, x, xbf);
  hipLaunchKernelGGL(persist_kernel, dim3(256), dim3(256), 0, stream,
                     x, xbf, td, w, bias, dw, dbias, dbeta, hb, flags, out);
}

// Round 8
// 1330.281 us; speedup vs baseline: 3.0616x; 2.1428x over previous
//
#include <hip/hip_runtime.h>

typedef unsigned short u16;
typedef unsigned int u32;
typedef unsigned long long u64;
typedef __bf16 bf16_t;
typedef bf16_t bf16x8 __attribute__((ext_vector_type(8)));
typedef u16 u16x8 __attribute__((ext_vector_type(8)));
typedef float f32x4 __attribute__((ext_vector_type(4)));

#define LL 256
#define SS 512

__device__ __forceinline__ u16 f2bf(float f) {
  unsigned u = __float_as_uint(f);
  u += 0x7fffu + ((u >> 16) & 1u);
  return (u16)(u >> 16);
}

union FragU { u16x8 u; bf16x8 h; u64 q[2]; };

__device__ __forceinline__ bf16x8 cvt8(const float* __restrict__ p) {
  float4 a = *(const float4*)p;
  float4 b = *(const float4*)(p + 4);
  FragU r;
  r.u[0] = f2bf(a.x); r.u[1] = f2bf(a.y); r.u[2] = f2bf(a.z); r.u[3] = f2bf(a.w);
  r.u[4] = f2bf(b.x); r.u[5] = f2bf(b.y); r.u[6] = f2bf(b.z); r.u[7] = f2bf(b.w);
  return r.h;
}

__device__ __forceinline__ float sigmoidf_(float v) { return 1.f / (1.f + __expf(-v)); }

__global__ void xconv_kernel(const float* __restrict__ x, u16* __restrict__ xbf) {
  const size_t n8 = 16777216 / 8;
  for (size_t i = (size_t)blockIdx.x * blockDim.x + threadIdx.x; i < n8;
       i += (size_t)gridDim.x * blockDim.x) {
    size_t di = i * 8;
    int t = (int)(di >> 16);
    int rem = (int)(di & 65535);
    int b = rem >> 9, d = rem & 511;
    FragU f;
    f.h = cvt8(x + (size_t)b * 131072 + (size_t)t * 512 + d);
    *(u16x8*)(xbf + di) = f.u;
  }
}

#define MFMA(a, b, c) __builtin_amdgcn_mfma_f32_16x16x32_bf16(a, b, c, 0, 0, 0)
#define ALOAD(p) __hip_atomic_load((p), __ATOMIC_RELAXED, __HIP_MEMORY_SCOPE_AGENT)
#define ASTORE(p, v) __hip_atomic_store((p), (v), __ATOMIC_RELAXED, __HIP_MEMORY_SCOPE_AGENT)

// Persistent scan. Grid 256 (PROVEN co-resident), 4 waves/WG. bb = wg&7 (16 batch rows),
// cg = wg>>3 (16 state cols -> 6 gate tiles + d tile = 7 MFMA tiles/wave). All cross-WG
// traffic via LLC-coherent relaxed agent atomics (the exact primitive set proven in r4).
// Sync: per-wave flag stores -> ONE aggregator wave per bb (cg==0,kq==0) polls 128 flags
// and publishes a single epoch word -> 128 consumer waves poll 1 dword (no congestion).
__global__ __launch_bounds__(256, 1) void persist_kernel(
    const float* __restrict__ x, const u16* __restrict__ xbf,
    const float* __restrict__ td,
    const float* __restrict__ w, const float* __restrict__ bias,
    const float* __restrict__ dw, const float* __restrict__ dbias,
    const float* __restrict__ dbeta,
    u16* __restrict__ hb, int* __restrict__ flags,
    float* __restrict__ out) {
  __shared__ __align__(16) float P[2][4][112][20];  // double-buffered reduce scratch
  const int wg = blockIdx.x;
  const int tid = threadIdx.x, kq = tid >> 6, l = tid & 63;
  const int bb = wg & 7, cg = wg >> 3;
  const int l15 = l & 15, lk = l >> 4;

  // ---- weight fragments into VGPRs (held for all 256 steps) ----
  bf16x8 wreg[8][7];
  const int kA = kq * 256 + lk * 8;
  {
#pragma unroll
    for (int n = 0; n < 6; ++n) {
      const float* wp = w + (size_t)(n * SS + cg * 16 + l15) * 1024 + kA;
#pragma unroll
      for (int ks = 0; ks < 8; ++ks) wreg[ks][n] = cvt8(wp + ks * 32);
    }
    if (l15 == 0) {
      const float* wp = dw + kA;
#pragma unroll
      for (int ks = 0; ks < 8; ++ks) wreg[ks][6] = cvt8(wp + ks * 32);
    } else {
#pragma unroll
      for (int ks = 0; ks < 8; ++ks) {
        FragU zf; zf.u = (u16x8){0, 0, 0, 0, 0, 0, 0, 0};
        wreg[ks][6] = zf.h;
      }
    }
  }

  // ---- per-thread state: thread owns (batch row r, state col jj) ----
  const int r = tid >> 4, jj = tid & 15;
  const int b = bb * 16 + r, s = cg * 16 + jj;
  float bia[6];
#pragma unroll
  for (int g = 0; g < 6; ++g) bia[g] = bias[g * SS + s];
  const float dbia = dbias[0], beta = dbeta[0];
  float cs = 0.f, ce = 0.f, o = 0.f, dreg = 0.f;

  int* const myflag = flags + bb * 128 + cg * 4 + kq;
  const int* const aggp = flags + bb * 128 + l * 2;   // aggregator: 2 flags/lane
  int* const ep = flags + 1024 + bb * 32;             // epoch word, own 128B region
  const bool is_agg = (cg == 0) && (kq == 0);
  float dtn = td[(size_t)b * LL];

  for (int t = 0; t < LL; ++t) {
    const int pb = t & 1;
    u16* hcur = hb + (size_t)pb * 65536;              // [8][32][16][16] u16 per buffer
    const int tgt = t + 1;

    // [1] every thread computes h_t for its cell; packed coherent store (full 64B lines)
    float dt_t = dtn;
    float c_t = cs + (ce - cs) * __expf(-dreg * dt_t);
    float h_t = o * (2.f * sigmoidf_(2.f * c_t) - 1.f);
    {
      u32 hv = f2bf(h_t);
      u32 nb = (u32)__shfl_down((int)hv, 1, 64);
      if ((tid & 1) == 0)
        ASTORE((u32*)(hcur + ((size_t)(bb * 32 + cg) * 256 + r * 16 + jj)), hv | (nb << 16));
    }

    // [2] drain h stores, then per-wave flag store (no RMW, own location)
    asm volatile("s_waitcnt vmcnt(0)" ::: "memory");
    if (l == 0) ASTORE(myflag, tgt);

    // deferred (acks hide under GEMM/poll): output write + next-dt prefetch
    out[((size_t)b * LL + t) * SS + s] = h_t;
    if (t + 1 < LL) dtn = td[(size_t)b * LL + (t + 1)];

    f32x4 acc[7] = {};
    if (kq < 2) {
      // [agg] one wave per bb: fold 128 flags -> 1 epoch word (the only raw-flag poller)
      if (is_agg) {
        for (;;) {
          int f0 = ALOAD(aggp);
          int f1 = ALOAD(aggp + 1);
          if (__all(min(f0, f1) >= tgt)) break;
        }
        if (l == 0) ASTORE(ep, tgt);
      }
      // [3a] x-waves: GEMM immediately (no h dependency)
      if (xbf) {
        const u16* xp = xbf + (size_t)t * 65536 + (size_t)(bb * 16 + l15) * 512 + kA;
#pragma unroll
        for (int ks = 0; ks < 8; ++ks) {
          bf16x8 a = *(const bf16x8*)(xp + ks * 32);
#pragma unroll
          for (int n = 0; n < 7; ++n) acc[n] = MFMA(a, wreg[ks][n], acc[n]);
        }
      } else {
        const float* xp = x + ((size_t)(bb * 16 + l15) * LL + t) * 512 + kA;
#pragma unroll
        for (int ks = 0; ks < 8; ++ks) {
          bf16x8 a = cvt8(xp + ks * 32);
#pragma unroll
          for (int n = 0; n < 7; ++n) acc[n] = MFMA(a, wreg[ks][n], acc[n]);
        }
      }
    } else if (t > 0) {
      // [3b] h-waves: poll ONE epoch dword, then load h fragments + GEMM
      while (ALOAD(ep) < tgt) {}
      __builtin_amdgcn_fence(__ATOMIC_ACQUIRE, "workgroup");  // compiler ordering only

      FragU fa[8];
#pragma unroll
      for (int ks = 0; ks < 8; ++ks) {
        const int sp = (kq - 2) * 256 + ks * 32 + lk * 8;  // h column base
        const int cg2 = sp >> 4, c0 = sp & 15;
        const u64* hp = (const u64*)(hcur + ((size_t)(bb * 32 + cg2) * 256 + l15 * 16 + c0));
        fa[ks].q[0] = ALOAD(hp);
        fa[ks].q[1] = ALOAD(hp + 1);
      }
#pragma unroll
      for (int ks = 0; ks < 8; ++ks)
#pragma unroll
        for (int n = 0; n < 7; ++n) acc[n] = MFMA(fa[ks].h, wreg[ks][n], acc[n]);
    }
    // (h-waves at t==0: h0 == 0, acc stays 0)

    // [4] spill partials (double-buffered LDS), one barrier, reduce + gates
#pragma unroll
    for (int n = 0; n < 7; ++n)
      *(f32x4*)&P[pb][kq][n * 16 + l15][lk * 4] = acc[n];
    __syncthreads();

    float pre[6];
#pragma unroll
    for (int g = 0; g < 6; ++g) {
      int col = g * 16 + jj;
      pre[g] = P[pb][0][col][r] + P[pb][1][col][r] + P[pb][2][col][r] + P[pb][3][col][r] + bia[g];
    }
    float dpre = P[pb][0][96][r] + P[pb][1][96][r] + P[pb][2][96][r] + P[pb][3][96][r] + dbia;

    float ig  = sigmoidf_(pre[0]);
    float fg  = sigmoidf_(pre[1]);
    float ieg = sigmoidf_(pre[2]);
    float feg = sigmoidf_(pre[3]);
    float z   = 2.f * sigmoidf_(pre[4]) - 1.f;
    float og  = sigmoidf_(pre[5]);

    cs = fg * c_t + ig * z;
    ce = feg * ce + ieg * z;
    o = og;
    float v = beta * dpre;
    float sp = (v > 15.f) ? v : log1pf(__expf(v));
    dreg = sp / beta;
  }

  // final_state = concat([o, cs, ce, d], axis=1), shape (1, 128, 1537)
  size_t fb = (size_t)16777216 + (size_t)b * 1537;
  out[fb + s] = o;
  out[fb + 512 + s] = cs;
  out[fb + 1024 + s] = ce;
  if (s == 0) out[fb + 1536] = dreg;
}

extern "C" void kernel_launch(void* const* d_in, const int* in_sizes, int n_in,
                              void* d_out, int out_size, void* d_ws, size_t ws_size,
                              hipStream_t stream) {
  const float* x     = (const float*)d_in[0];
  const float* td    = (const float*)d_in[1];
  const float* w     = (const float*)d_in[2];
  const float* bias  = (const float*)d_in[3];
  const float* dw    = (const float*)d_in[4];
  const float* dbias = (const float*)d_in[5];
  const float* dbeta = (const float*)d_in[6];
  float* out = (float*)d_out;

  char* ws = (char*)d_ws;
  u16* hb    = (u16*)ws;                  // [2][8][32][16][16] bf16 = 262,144 B
  int* flags = (int*)(ws + 262144);       // 1024 wave flags + 8 epochs*32 = 5,120 B
  const size_t XBF_OFF = 262144 + 5120;
  const size_t NEED = XBF_OFF + 33554432;
  u16* xbf = (ws_size >= NEED) ? (u16*)(ws + XBF_OFF) : nullptr;

  hipMemsetAsync(flags, 0, 5120, stream);
  if (xbf) hipLaunchKernelGGL(xconv_kernel, dim3(2048), dim3(256), 0, stream, x, xbf);
  hipLaunchKernelGGL(persist_kernel, dim3(256), dim3(256), 0, stream,
                     x, xbf, td, w, bias, dw, dbias, dbeta, hb, flags, out);
}